// Round 11
// baseline (450.943 us; speedup 1.0000x reference)
//
#include <hip/hip_runtime.h>
#include <hip/hip_fp16.h>

// PathGCN fused layer — fp32 math, f16 gather operand.
// out[n,j] = relu( sum_k res[n,k] * fcw[j,k] )
// res[n,k] = (1/8) * sum_l pw[l,k] * ( sum_p feats[ paths[p,n,l], k ] )
//
// R11 == R10 resubmit (container infra died pre-launch; kernel audited:
// in-bounds, uniform barriers, graph-capture-safe, exact 6250-block grid).
// R10: halve gather instruction count. R4->R9 history shows time ~ FETCH
// bytes at a constant ~3.3 TB/s L3->L2 rate; occupancy/barriers/MLP moved
// <=10%. Remaining lever: issue efficiency. 16 lanes x uint4 (16 B/lane)
// per feats row -> NPB=16, half the load instrs + addr VALU, 1 KB per
// wave-load, half the fcw staging (6250 blocks). Phase 2 remapped:
// thread (node 0..15, c 0..15) owns j = c+16*jj, jj=0..7; fcwt reads are
// 16-lane broadcast groups (conflict-free, pad-33). 8-deep MLP kept (R9).

#define N_NODES 100000
#define HIDDEN  128
#define NPATH   8
#define PLEN    8
#define NPB     16     // nodes per block (256 threads = 16 nodes x 16 lanes)
#define KT      32     // k-tile width for fcw staging

// ---------------- Kernel 0: feats f32 -> f16 copy (workspace) ----------------
__global__ void PathGCNLayer_61306363183203_tohalf(
    const float4* __restrict__ feats4,   // (N*32) float4
    uint2*        __restrict__ fh)       // (N*32) uint2 = 4 halfs
{
    const size_t i = (size_t)blockIdx.x * blockDim.x + threadIdx.x;
    if (i < (size_t)N_NODES * 32) {
        const float4 v = feats4[i];
        __half2 a = __floats2half2_rn(v.x, v.y);
        __half2 b = __floats2half2_rn(v.z, v.w);
        uint2 o;
        o.x = *reinterpret_cast<unsigned int*>(&a);
        o.y = *reinterpret_cast<unsigned int*>(&b);
        fh[i] = o;
    }
}

// ---------------- Kernel 1: fused gather(f16,16B/lane) + einsum + GEMM + ReLU ----
__global__ void PathGCNLayer_61306363183203_fused_h16(
    const uint4*  __restrict__ feats_h4, // (N, 16) rows of uint4 (8 halfs)
    const int*    __restrict__ paths,    // (8, N, 8) int32
    const float4* __restrict__ pw4,      // (8, 32) float4 rows
    const float4* __restrict__ fcw4,     // (128, 32) float4 rows
    float*        __restrict__ out)      // (N, 128) f32
{
    __shared__ int    sidx[NPATH * NPB * PLEN];  // [p][node][l], p-major (4 KB)
    __shared__ float4 sres4[NPB][33];            // res tile (8.4 KB)
    __shared__ float  fcwt[HIDDEN][KT + 1];      // fcw k-tile, pad 33 (16.9 KB)

    const int tid  = threadIdx.x;
    const int n0   = blockIdx.x * NPB;
    const int node = tid >> 4;      // 0..15
    const int c    = tid & 15;      // uint4 column within row (16 B granule)

    // ---- stage 1024 path indices (for each p: 128 consecutive ints) ----
    {
        const int p = tid >> 5;     // 0..7
        const int i = tid & 31;
        const size_t base = (size_t)p * (N_NODES * PLEN) + (size_t)n0 * PLEN;
        sidx[p * 128 + i]      = paths[base + i];
        sidx[p * 128 + i + 32] = paths[base + i + 32];
        sidx[p * 128 + i + 64] = paths[base + i + 64];
        sidx[p * 128 + i + 96] = paths[base + i + 96];
    }
    __syncthreads();

    // ---- phase 1: res[node][8c..8c+7], 8-deep load batch per l-group ----
    float a0 = 0.f, a1 = 0.f, a2 = 0.f, a3 = 0.f,
          a4 = 0.f, a5 = 0.f, a6 = 0.f, a7 = 0.f;
    #pragma unroll
    for (int l = 0; l < PLEN; ++l) {
        uint4 hv0, hv1, hv2, hv3, hv4, hv5, hv6, hv7;
        {
            const int i0 = sidx[0 * 128 + node * PLEN + l];
            const int i1 = sidx[1 * 128 + node * PLEN + l];
            const int i2 = sidx[2 * 128 + node * PLEN + l];
            const int i3 = sidx[3 * 128 + node * PLEN + l];
            const int i4 = sidx[4 * 128 + node * PLEN + l];
            const int i5 = sidx[5 * 128 + node * PLEN + l];
            const int i6 = sidx[6 * 128 + node * PLEN + l];
            const int i7 = sidx[7 * 128 + node * PLEN + l];
            hv0 = feats_h4[(size_t)i0 * 16 + c];
            hv1 = feats_h4[(size_t)i1 * 16 + c];
            hv2 = feats_h4[(size_t)i2 * 16 + c];
            hv3 = feats_h4[(size_t)i3 * 16 + c];
            hv4 = feats_h4[(size_t)i4 * 16 + c];
            hv5 = feats_h4[(size_t)i5 * 16 + c];
            hv6 = feats_h4[(size_t)i6 * 16 + c];
            hv7 = feats_h4[(size_t)i7 * 16 + c];
        }
        float s0 = 0.f, s1 = 0.f, s2 = 0.f, s3 = 0.f,
              s4 = 0.f, s5 = 0.f, s6 = 0.f, s7 = 0.f;
        #define ACC8(hv)                                                            \
        {                                                                           \
            const float2 f0 = __half22float2(*reinterpret_cast<const __half2*>(&hv.x)); \
            const float2 f1 = __half22float2(*reinterpret_cast<const __half2*>(&hv.y)); \
            const float2 f2 = __half22float2(*reinterpret_cast<const __half2*>(&hv.z)); \
            const float2 f3 = __half22float2(*reinterpret_cast<const __half2*>(&hv.w)); \
            s0 += f0.x; s1 += f0.y; s2 += f1.x; s3 += f1.y;                         \
            s4 += f2.x; s5 += f2.y; s6 += f3.x; s7 += f3.y;                         \
        }
        ACC8(hv0) ACC8(hv1) ACC8(hv2) ACC8(hv3)
        ACC8(hv4) ACC8(hv5) ACC8(hv6) ACC8(hv7)
        #undef ACC8
        const float4 w0 = pw4[l * 32 + 2 * c];
        const float4 w1 = pw4[l * 32 + 2 * c + 1];
        a0 = fmaf(s0, w0.x, a0);
        a1 = fmaf(s1, w0.y, a1);
        a2 = fmaf(s2, w0.z, a2);
        a3 = fmaf(s3, w0.w, a3);
        a4 = fmaf(s4, w1.x, a4);
        a5 = fmaf(s5, w1.y, a5);
        a6 = fmaf(s6, w1.z, a6);
        a7 = fmaf(s7, w1.w, a7);
    }
    {
        float4 r0, r1;
        r0.x = a0 * 0.125f; r0.y = a1 * 0.125f; r0.z = a2 * 0.125f; r0.w = a3 * 0.125f;
        r1.x = a4 * 0.125f; r1.y = a5 * 0.125f; r1.z = a6 * 0.125f; r1.w = a7 * 0.125f;
        sres4[node][2 * c]     = r0;
        sres4[node][2 * c + 1] = r1;
    }

    // ---- phase 2: out[node][j], j = c + 16*jj (jj=0..7), 4 fcw k-tiles ----
    float o0 = 0.f, o1 = 0.f, o2 = 0.f, o3 = 0.f,
          o4 = 0.f, o5 = 0.f, o6 = 0.f, o7 = 0.f;

    #pragma unroll
    for (int kt = 0; kt < HIDDEN / KT; ++kt) {
        __syncthreads();   // protect fcwt reuse (and sres on first iter)
        {
            const int j    = tid >> 1;        // 0..127
            const int half = tid & 1;         // 0..1
            const int gbase = j * 32 + kt * (KT / 4) + half * 4;
            const int lbase = half * 16;
            #pragma unroll
            for (int q = 0; q < 4; ++q) {
                const float4 v = fcw4[gbase + q];
                fcwt[j][lbase + q * 4 + 0] = v.x;
                fcwt[j][lbase + q * 4 + 1] = v.y;
                fcwt[j][lbase + q * 4 + 2] = v.z;
                fcwt[j][lbase + q * 4 + 3] = v.w;
            }
        }
        __syncthreads();

        #pragma unroll
        for (int kc = 0; kc < KT / 4; ++kc) {
            const float4 rv = sres4[node][kt * (KT / 4) + kc];  // broadcast per 16-lane group
            const int k0 = kc * 4;
            #pragma unroll
            for (int jj = 0; jj < 8; ++jj) {
                const int j = c + 16 * jj;
                float* op = (jj == 0) ? &o0 : (jj == 1) ? &o1 : (jj == 2) ? &o2 :
                            (jj == 3) ? &o3 : (jj == 4) ? &o4 : (jj == 5) ? &o5 :
                            (jj == 6) ? &o6 : &o7;
                float o = *op;
                o = fmaf(rv.x, fcwt[j][k0    ], o);
                o = fmaf(rv.y, fcwt[j][k0 + 1], o);
                o = fmaf(rv.z, fcwt[j][k0 + 2], o);
                o = fmaf(rv.w, fcwt[j][k0 + 3], o);
                *op = o;
            }
        }
    }

    // ReLU + store: per jj, 16 consecutive floats per node (coalesced 64B runs)
    {
        const size_t obase = (size_t)(n0 + node) * HIDDEN + c;
        out[obase      ] = o0 > 0.f ? o0 : 0.f;
        out[obase + 16 ] = o1 > 0.f ? o1 : 0.f;
        out[obase + 32 ] = o2 > 0.f ? o2 : 0.f;
        out[obase + 48 ] = o3 > 0.f ? o3 : 0.f;
        out[obase + 64 ] = o4 > 0.f ? o4 : 0.f;
        out[obase + 80 ] = o5 > 0.f ? o5 : 0.f;
        out[obase + 96 ] = o6 > 0.f ? o6 : 0.f;
        out[obase + 112] = o7 > 0.f ? o7 : 0.f;
    }
}

// ---------------- Fallback: R0's fused f32 kernel (proven) ----------------
__global__ void PathGCNLayer_61306363183203_fused(
    const float4* __restrict__ feats4,
    const int*    __restrict__ paths,
    const float4* __restrict__ pw4,
    const float4* __restrict__ fcw4,
    float*        __restrict__ out)
{
    __shared__ int    sidx[NPATH * 8 * PLEN];
    __shared__ float4 sres4[8][33];
    __shared__ float  fcwt[HIDDEN][KT + 1];

    const int tid  = threadIdx.x;
    const int n0   = blockIdx.x * 8;
    const int node = tid >> 5;
    const int c    = tid & 31;

    {
        const int p = tid >> 5;
        const int i = tid & 31;
        const size_t base = (size_t)p * (N_NODES * PLEN) + (size_t)n0 * PLEN;
        sidx[p * 64 + i]      = paths[base + i];
        sidx[p * 64 + i + 32] = paths[base + i + 32];
    }
    __syncthreads();

    float ax = 0.0f, ay = 0.0f, az = 0.0f, aw = 0.0f;
    #pragma unroll
    for (int l = 0; l < PLEN; ++l) {
        float sx = 0.0f, sy = 0.0f, sz = 0.0f, sw = 0.0f;
        #pragma unroll
        for (int p = 0; p < NPATH; ++p) {
            const int idx = sidx[p * 64 + node * PLEN + l];
            const float4 v = feats4[(size_t)idx * 32 + c];
            sx += v.x; sy += v.y; sz += v.z; sw += v.w;
        }
        const float4 w = pw4[l * 32 + c];
        ax = fmaf(sx, w.x, ax);
        ay = fmaf(sy, w.y, ay);
        az = fmaf(sz, w.z, az);
        aw = fmaf(sw, w.w, aw);
    }
    {
        float4 r;
        r.x = ax * 0.125f; r.y = ay * 0.125f;
        r.z = az * 0.125f; r.w = aw * 0.125f;
        sres4[node][c] = r;
    }

    float o0 = 0.0f, o1 = 0.0f, o2 = 0.0f, o3 = 0.0f;
    #pragma unroll
    for (int kt = 0; kt < HIDDEN / KT; ++kt) {
        __syncthreads();
        {
            const int j    = tid >> 1;
            const int half = tid & 1;
            const int gbase = j * 32 + kt * (KT / 4) + half * 4;
            const int lbase = half * 16;
            #pragma unroll
            for (int q = 0; q < 4; ++q) {
                const float4 v = fcw4[gbase + q];
                fcwt[j][lbase + q * 4 + 0] = v.x;
                fcwt[j][lbase + q * 4 + 1] = v.y;
                fcwt[j][lbase + q * 4 + 2] = v.z;
                fcwt[j][lbase + q * 4 + 3] = v.w;
            }
        }
        __syncthreads();
        #pragma unroll
        for (int kc = 0; kc < KT / 4; ++kc) {
            const float4 rv = sres4[node][kt * (KT / 4) + kc];
            const int k0 = kc * 4;
            o0 = fmaf(rv.x, fcwt[c      ][k0    ], o0);
            o1 = fmaf(rv.x, fcwt[c + 32 ][k0    ], o1);
            o2 = fmaf(rv.x, fcwt[c + 64 ][k0    ], o2);
            o3 = fmaf(rv.x, fcwt[c + 96 ][k0    ], o3);
            o0 = fmaf(rv.y, fcwt[c      ][k0 + 1], o0);
            o1 = fmaf(rv.y, fcwt[c + 32 ][k0 + 1], o1);
            o2 = fmaf(rv.y, fcwt[c + 64 ][k0 + 1], o2);
            o3 = fmaf(rv.y, fcwt[c + 96 ][k0 + 1], o3);
            o0 = fmaf(rv.z, fcwt[c      ][k0 + 2], o0);
            o1 = fmaf(rv.z, fcwt[c + 32 ][k0 + 2], o1);
            o2 = fmaf(rv.z, fcwt[c + 64 ][k0 + 2], o2);
            o3 = fmaf(rv.z, fcwt[c + 96 ][k0 + 2], o3);
            o0 = fmaf(rv.w, fcwt[c      ][k0 + 3], o0);
            o1 = fmaf(rv.w, fcwt[c + 32 ][k0 + 3], o1);
            o2 = fmaf(rv.w, fcwt[c + 64 ][k0 + 3], o2);
            o3 = fmaf(rv.w, fcwt[c + 96 ][k0 + 3], o3);
        }
    }
    {
        const size_t obase = (size_t)(n0 + node) * HIDDEN + c;
        out[obase]      = o0 > 0.0f ? o0 : 0.0f;
        out[obase + 32] = o1 > 0.0f ? o1 : 0.0f;
        out[obase + 64] = o2 > 0.0f ? o2 : 0.0f;
        out[obase + 96] = o3 > 0.0f ? o3 : 0.0f;
    }
}

extern "C" void kernel_launch(void* const* d_in, const int* in_sizes, int n_in,
                              void* d_out, int out_size, void* d_ws, size_t ws_size,
                              hipStream_t stream) {
    const float4* feats4 = (const float4*)d_in[0];  // (N,128) f32
    const int*    paths  = (const int*)d_in[1];     // (8,N,8) int32
    // d_in[2] = init_feats — unused by the reference
    const float4* pw4    = (const float4*)d_in[3];  // (1,8,128) f32
    const float4* fcw4   = (const float4*)d_in[4];  // (128,128) f32
    float* out = (float*)d_out;
    (void)in_sizes; (void)n_in; (void)out_size;

    const size_t half_bytes = (size_t)N_NODES * HIDDEN * sizeof(unsigned short); // 25.6 MB
    if (d_ws != nullptr && ws_size >= half_bytes) {
        uint2* fh = (uint2*)d_ws;
        const int cvt_blocks = (N_NODES * 32 + 255) / 256;   // 3.2M float4s
        PathGCNLayer_61306363183203_tohalf<<<cvt_blocks, 256, 0, stream>>>(feats4, fh);
        PathGCNLayer_61306363183203_fused_h16<<<N_NODES / NPB, 256, 0, stream>>>(
            (const uint4*)d_ws, paths, pw4, fcw4, out);
    } else {
        PathGCNLayer_61306363183203_fused<<<N_NODES / 8, 256, 0, stream>>>(
            feats4, paths, pw4, fcw4, out);
    }
}